// Round 3
// baseline (263.606 us; speedup 1.0000x reference)
//
#include <hip/hip_runtime.h>

#define NNODES 8192
#define NEDGES 65536

#define K_PACK   0.02209708691f   // 1/sqrt(2048)
#define K_P1SV   0.01804219593f   // 1/(32*sqrt3)
#define K_VVS    0.04419417382f   // 1/sqrt(512)
#define K_VS     0.03608439182f   // 1/(16*sqrt3)
#define K_VVV    0.02551551815f   // K_VS/sqrt2
#define K_DOT    0.57735026919f
#define K_PRELN  0.35355339059f
#define C_EMB    8.4335730689f

typedef unsigned int uint32;
typedef unsigned short ushort16;
typedef __attribute__((ext_vector_type(8))) short short8;
typedef __attribute__((ext_vector_type(4))) float floatx4;

__device__ __forceinline__ float siluf(float x) { return x / (1.0f + __expf(-x)); }
__device__ __forceinline__ float susf(float t) { return t > 0.0f ? __expf(-1.0f / t) : 0.0f; }
__device__ __forceinline__ ushort16 f2bf(float f) {
  uint32 u = __float_as_uint(f);
  return (ushort16)((u + 0x7fffu + ((u >> 16) & 1u)) >> 16);
}
__device__ __forceinline__ float bflo(uint32 v) { return __uint_as_float(v << 16); }
__device__ __forceinline__ float bfhi(uint32 v) { return __uint_as_float(v & 0xffff0000u); }

__device__ __forceinline__ void mlp32(const float* __restrict__ W, const float emb[10],
                                      float* __restrict__ H) {
#pragma unroll
  for (int m = 0; m < 32; ++m) {
    float t = 0.f;
#pragma unroll
    for (int k = 0; k < 10; ++k) t += emb[k] * W[k * 32 + m];
    H[m] = siluf(t);
  }
}

// ---------- prep: edge geom/MLPs, deg histograms (dst+src), combo, X0cb, B packs ----------
__global__ __launch_bounds__(256) void k_prep(
    const float* __restrict__ pos, const int* __restrict__ z, const int* __restrict__ mol,
    const int* __restrict__ esrc, const int* __restrict__ edst,
    const float* __restrict__ Ez, const float* __restrict__ Em,
    const float* __restrict__ W10, const float* __restrict__ W11, const float* __restrict__ W12,
    const float* __restrict__ W20, const float* __restrict__ W21, const float* __restrict__ W22,
    int* __restrict__ combo, ushort16* __restrict__ X0cb, float* __restrict__ sh,
    float* __restrict__ h0, float* __restrict__ h1, float* __restrict__ h2,
    ushort16* __restrict__ h1b, ushort16* __restrict__ h2b,
    ushort16* __restrict__ Bp0, ushort16* __restrict__ Bp1, ushort16* __restrict__ Bp2,
    ushort16* __restrict__ Bpw1, ushort16* __restrict__ Bpw2, int* __restrict__ deg) {
  int idx = blockIdx.x * 256 + threadIdx.x;
  if (idx < NEDGES) {
    int e = idx;
    int s = esrc[e], d = edst[e];
    atomicAdd(&deg[d], 1);
    atomicAdd(&deg[NNODES + s], 1);
    float vx = pos[d * 3 + 0] - pos[s * 3 + 0];
    float vy = pos[d * 3 + 1] - pos[s * 3 + 1];
    float vz = pos[d * 3 + 2] - pos[s * 3 + 2];
    float len = sqrtf(vx * vx + vy * vy + vz * vz);
    float inv = 1.7320508076f / fmaxf(len, 1e-9f);
    sh[e * 3 + 0] = vx * inv; sh[e * 3 + 1] = vy * inv; sh[e * 3 + 2] = vz * inv;
    float emb[10];
#pragma unroll
    for (int k = 0; k < 10; ++k) {
      float u = len * 1.1f - (float)(k + 1);
      emb[k] = C_EMB * susf(u + 1.0f) * susf(1.0f - u);
    }
    float H[32];
    mlp32(W10, emb, H);
#pragma unroll
    for (int m = 0; m < 32; ++m) h0[(size_t)e * 32 + m] = H[m];
    mlp32(W11, emb, H);
#pragma unroll
    for (int m = 0; m < 32; ++m) {
      h1[(size_t)e * 32 + m] = H[m];
      h1b[(size_t)e * 32 + m] = f2bf(H[m]);
    }
    mlp32(W12, emb, H);
#pragma unroll
    for (int m = 0; m < 32; ++m) {
      h2[(size_t)e * 32 + m] = H[m];
      h2b[(size_t)e * 32 + m] = f2bf(H[m]);
    }
    return;
  }
  idx -= NEDGES;
  if (idx < NNODES) { combo[idx] = z[idx] * 2 + mol[idx]; return; }
  idx -= NNODES;
  if (idx < 16384) {  // X0cb[256][64] bf16
    int c = idx >> 6, j = idx & 63;
    float v = 0.f;
    if (c < 200) {
      int zz = c >> 1, mm = c & 1;
      v = (j < 48) ? Ez[zz * 48 + j] : Em[mm * 16 + (j - 48)];
    }
    X0cb[idx] = f2bf(v);
    return;
  }
  idx -= 16384;
  if (idx < 81920) {  // Bp0[tile(80)][kh(2)][lane(64)][j(8)] bf16, K=64
    int tile = idx >> 10; int r = idx & 1023;
    int kh = r >> 9; int rr = r & 511;
    int lane = rr >> 3, j = rr & 7;
    int k = kh * 32 + (lane >> 4) * 8 + j;
    int n = tile * 16 + (lane & 15);
    int c = n >> 5, m = n & 31;
    int col = (c < 32) ? (k * 32 + c) : (2048 + k * 8 + (c - 32));
    Bp0[idx] = f2bf(W20[m * 2560 + col] * K_PACK);
    return;
  }
  idx -= 81920;
  if (idx < 40960) {  // Bp1[tile(80)][lane][j] bf16, K=32
    int tile = idx >> 9; int rr = idx & 511;
    int lane = rr >> 3, j = rr & 7;
    int k = (lane >> 4) * 8 + j;
    int n = tile * 16 + (lane & 15);
    int c = n >> 5, m = n & 31;
    float v = (c < 32) ? W21[m * 1664 + k * 32 + c] * K_PACK
                       : W21[m * 1664 + 1280 + k * 8 + (c - 32)] * K_P1SV;
    Bp1[idx] = f2bf(v);
    return;
  }
  idx -= 40960;
  if (idx < 16384) {  // Bp2[tile(32)][lane][j] bf16, K=32
    int tile = idx >> 9; int rr = idx & 511;
    int lane = rr >> 3, j = rr & 7;
    int k = (lane >> 4) * 8 + j;
    int n = tile * 16 + (lane & 15);
    int c = n >> 5, m = n & 31;
    Bp2[idx] = f2bf(W22[m * 640 + k * 16 + c] * K_PACK);
    return;
  }
  idx -= 16384;
  if (idx < 12288) {  // Bpw1: per-edge weights, col n: [w<32][u] vvs | [v][u] vs | [v][u] vvv
    int tile = idx >> 9; int rr = idx & 511;
    int lane = rr >> 3, j = rr & 7;
    int m = (lane >> 4) * 8 + j;
    int n = tile * 16 + (lane & 15);
    float v;
    if (n < 256) {              // n = c*8 + u  (vvs: output c, input u)
      int c = n >> 3, u = n & 7;
      v = W21[m * 1664 + 1024 + u * 32 + c] * K_VVS;
    } else if (n < 320) {       // n = 256 + vo*8 + u  (vs)
      int vo = (n - 256) >> 3, u = n & 7;
      v = W21[m * 1664 + 1536 + u * 8 + vo] * K_VS;
    } else {                    // n = 320 + vo*8 + u  (vvv)
      int vo = (n - 320) >> 3, u = n & 7;
      v = W21[m * 1664 + 1600 + u * 8 + vo] * K_VVV;
    }
    Bpw1[idx] = f2bf(v);
    return;
  }
  idx -= 12288;
  {  // Bpw2: col n = c*8 + u -> W22 vvs weights
    int tile = idx >> 9; int rr = idx & 511;
    int lane = rr >> 3, j = rr & 7;
    int m = (lane >> 4) * 8 + j;
    int n = tile * 16 + (lane & 15);
    int c = n >> 3, u = n & 7;
    Bpw2[idx] = f2bf(W22[m * 640 + 512 + u * 16 + c] * K_VVS);
  }
}

// ---------- exclusive scan: block 0 -> dst rowptr, block 1 -> src rowptr ----------
__global__ __launch_bounds__(256) void k_scan(const int* __restrict__ deg,
                                              int* __restrict__ rowptr) {
  const int* in = deg + blockIdx.x * NNODES;
  int* out = rowptr + blockIdx.x * (NNODES + 1);
  __shared__ int sums[256];
  int t = threadIdx.x;
  int base = t * 32;
  int local[32];
  int s = 0;
#pragma unroll
  for (int i = 0; i < 32; ++i) { local[i] = s; s += in[base + i]; }
  sums[t] = s;
  __syncthreads();
  for (int off = 1; off < 256; off <<= 1) {
    int v = (t >= off) ? sums[t - off] : 0;
    __syncthreads();
    sums[t] += v;
    __syncthreads();
  }
  int prev = (t == 0) ? 0 : sums[t - 1];
#pragma unroll
  for (int i = 0; i < 32; ++i) out[base + i] = prev + local[i];
  if (t == 255) out[NNODES] = sums[255];
}

// ---------- fill both CSR edge-index arrays ----------
__global__ __launch_bounds__(256) void k_fill(
    const int* __restrict__ esrc, const int* __restrict__ edst,
    const int* __restrict__ rowptr, int* __restrict__ fill, int* __restrict__ eidx) {
  int t = blockIdx.x * 256 + threadIdx.x;
  if (t < NEDGES) {
    int d = edst[t];
    int p = atomicAdd(&fill[d], 1);
    eidx[rowptr[d] + p] = t;
  } else {
    int e = t - NEDGES;
    if (e < NEDGES) {
      int s = esrc[e];
      int p = atomicAdd(&fill[NNODES + s], 1);
      eidx[NEDGES + rowptr[NNODES + 1 + s] + p] = e;
    }
  }
}

// ---------- MFMA GEMM: C[M,N](bf16) = A[M,K](bf16) @ Bp(frag-packed bf16); K in {32,64} ----------
__global__ __launch_bounds__(256) void k_gemm_mfma(
    const ushort16* __restrict__ A, const ushort16* __restrict__ Bp, ushort16* __restrict__ C,
    int N, int K) {
  int wave = threadIdx.x >> 6, lane = threadIdx.x & 63;
  int m0 = blockIdx.x * 64 + wave * 16;
  int n0 = blockIdx.y * 64;
  int row = lane & 15, q = lane >> 4;
  int nkh = K >> 5;
  floatx4 acc[4];
  floatx4 zero = {0.f, 0.f, 0.f, 0.f};
#pragma unroll
  for (int t = 0; t < 4; ++t) acc[t] = zero;
  for (int kh = 0; kh < nkh; ++kh) {
    short8 a = *reinterpret_cast<const short8*>(A + (size_t)(m0 + row) * K + kh * 32 + q * 8);
#pragma unroll
    for (int t = 0; t < 4; ++t) {
      int T = (n0 >> 4) + t;
      short8 b = *reinterpret_cast<const short8*>(Bp + ((size_t)T * nkh + kh) * 512 + lane * 8);
      acc[t] = __builtin_amdgcn_mfma_f32_16x16x32_bf16(a, b, acc[t], 0, 0, 0);
    }
  }
  int colb = n0 + row;
#pragma unroll
  for (int t = 0; t < 4; ++t)
#pragma unroll
    for (int r = 0; r < 4; ++r)
      C[(size_t)(m0 + q * 4 + r) * N + colb + t * 16] = f2bf(acc[t][r]);
}

// ---------- block-0 message, src-node-major: P row in regs, loop out-edges ----------
__global__ __launch_bounds__(256) void k_msg0n(
    const int* __restrict__ rowptr_s, const int* __restrict__ eidx_s,
    const int* __restrict__ combo, const float* __restrict__ sh,
    const float* __restrict__ h, const ushort16* __restrict__ Pb, float* __restrict__ msg) {
  int n = __builtin_amdgcn_readfirstlane(blockIdx.x * 4 + (threadIdx.x >> 6));
  int lane = threadIdx.x & 63;
  int l = lane - 32;
  int vi = (l >= 0) ? ((l / 3 > 7) ? 7 : l / 3) : 0;
  int ii = (l >= 0) ? (l - (l / 3) * 3) : 0;
  int cp = (lane < 32) ? lane : 32 + vi;
  int row = combo[n];
  const uint4* Pp = reinterpret_cast<const uint4*>(Pb + (size_t)row * 1280 + cp * 32);
  uint4 P0 = Pp[0], P1 = Pp[1], P2 = Pp[2], P3 = Pp[3];
  int r0 = rowptr_s[n], r1 = rowptr_s[n + 1];
  for (int j = r0; j < r1; ++j) {
    int e = __builtin_amdgcn_readfirstlane(eidx_s[j]);
    float sh0 = sh[e * 3 + 0], sh1 = sh[e * 3 + 1], sh2 = sh[e * 3 + 2];
    const float* hp = h + (size_t)e * 32;
    float a = 0.f;
    a += bflo(P0.x) * hp[0] + bfhi(P0.x) * hp[1] + bflo(P0.y) * hp[2] + bfhi(P0.y) * hp[3];
    a += bflo(P0.z) * hp[4] + bfhi(P0.z) * hp[5] + bflo(P0.w) * hp[6] + bfhi(P0.w) * hp[7];
    a += bflo(P1.x) * hp[8] + bfhi(P1.x) * hp[9] + bflo(P1.y) * hp[10] + bfhi(P1.y) * hp[11];
    a += bflo(P1.z) * hp[12] + bfhi(P1.z) * hp[13] + bflo(P1.w) * hp[14] + bfhi(P1.w) * hp[15];
    a += bflo(P2.x) * hp[16] + bfhi(P2.x) * hp[17] + bflo(P2.y) * hp[18] + bfhi(P2.y) * hp[19];
    a += bflo(P2.z) * hp[20] + bfhi(P2.z) * hp[21] + bflo(P2.w) * hp[22] + bfhi(P2.w) * hp[23];
    a += bflo(P3.x) * hp[24] + bfhi(P3.x) * hp[25] + bflo(P3.y) * hp[26] + bfhi(P3.y) * hp[27];
    a += bflo(P3.z) * hp[28] + bfhi(P3.z) * hp[29] + bflo(P3.w) * hp[30] + bfhi(P3.w) * hp[31];
    float mult = (lane < 32) ? 1.0f : ((ii == 0) ? sh0 : (ii == 1) ? sh1 : sh2);
    if (lane < 56) msg[(size_t)e * 56 + lane] = a * mult;
  }
}

// ---------- block-1 message, src-node-major: fused P + vvs/vs/vvv, lane owns channel ----------
__global__ __launch_bounds__(256) void k_msg1n(
    const int* __restrict__ rowptr_s, const int* __restrict__ eidx_s,
    const float* __restrict__ sh, const float* __restrict__ h,
    const ushort16* __restrict__ Pb, const float* __restrict__ xv,
    const ushort16* __restrict__ Wedge, float* __restrict__ msg) {
  int n = __builtin_amdgcn_readfirstlane(blockIdx.x * 4 + (threadIdx.x >> 6));
  int lane = threadIdx.x & 63;
  int l = lane - 32;
  int vi = (l >= 0) ? ((l / 3 > 7) ? 7 : l / 3) : 0;
  int ii = (l >= 0) ? (l - (l / 3) * 3) : 0;
  int cp = (lane < 32) ? lane : 32 + vi;
  const uint4* Pp = reinterpret_cast<const uint4*>(Pb + (size_t)n * 1280 + cp * 32);
  uint4 P0 = Pp[0], P1 = Pp[1], P2 = Pp[2], P3 = Pp[3];
  const float* xvp = xv + (size_t)n * 24;   // wave-uniform -> SGPRs
  float xr[24];
#pragma unroll
  for (int t = 0; t < 24; ++t) xr[t] = xvp[t];
  int r0 = rowptr_s[n], r1 = rowptr_s[n + 1];
  for (int j = r0; j < r1; ++j) {
    int e = __builtin_amdgcn_readfirstlane(eidx_s[j]);
    float sh0 = sh[e * 3 + 0], sh1 = sh[e * 3 + 1], sh2 = sh[e * 3 + 2];
    const float* hp = h + (size_t)e * 32;
    float a = 0.f;
    a += bflo(P0.x) * hp[0] + bfhi(P0.x) * hp[1] + bflo(P0.y) * hp[2] + bfhi(P0.y) * hp[3];
    a += bflo(P0.z) * hp[4] + bfhi(P0.z) * hp[5] + bflo(P0.w) * hp[6] + bfhi(P0.w) * hp[7];
    a += bflo(P1.x) * hp[8] + bfhi(P1.x) * hp[9] + bflo(P1.y) * hp[10] + bfhi(P1.y) * hp[11];
    a += bflo(P1.z) * hp[12] + bfhi(P1.z) * hp[13] + bflo(P1.w) * hp[14] + bfhi(P1.w) * hp[15];
    a += bflo(P2.x) * hp[16] + bfhi(P2.x) * hp[17] + bflo(P2.y) * hp[18] + bfhi(P2.y) * hp[19];
    a += bflo(P2.z) * hp[20] + bfhi(P2.z) * hp[21] + bflo(P2.w) * hp[22] + bfhi(P2.w) * hp[23];
    a += bflo(P3.x) * hp[24] + bfhi(P3.x) * hp[25] + bflo(P3.y) * hp[26] + bfhi(P3.y) * hp[27];
    a += bflo(P3.z) * hp[28] + bfhi(P3.z) * hp[29] + bflo(P3.w) * hp[30] + bfhi(P3.w) * hp[31];
    const ushort16* wp = Wedge + (size_t)e * 384;
    float vterm, mult;
    if (lane < 32) {
      mult = 1.0f;
      float du[8];
#pragma unroll
      for (int u = 0; u < 8; ++u)
        du[u] = K_DOT * (xr[u * 3] * sh0 + xr[u * 3 + 1] * sh1 + xr[u * 3 + 2] * sh2);
      uint4 wv = *reinterpret_cast<const uint4*>(wp + lane * 8);
      vterm = du[0] * bflo(wv.x) + du[1] * bfhi(wv.x) + du[2] * bflo(wv.y) + du[3] * bfhi(wv.y)
            + du[4] * bflo(wv.z) + du[5] * bfhi(wv.z) + du[6] * bflo(wv.w) + du[7] * bfhi(wv.w);
    } else {
      float shi = (ii == 0) ? sh0 : (ii == 1) ? sh1 : sh2;
      float s1 = (ii == 0) ? sh1 : (ii == 1) ? sh2 : sh0;   // sh[(ii+1)%3]
      float s2 = (ii == 0) ? sh2 : (ii == 1) ? sh0 : sh1;   // sh[(ii+2)%3]
      mult = shi;
      uint4 wvs = *reinterpret_cast<const uint4*>(wp + 256 + vi * 8);
      uint4 wvv = *reinterpret_cast<const uint4*>(wp + 320 + vi * 8);
      float vsw[8] = {bflo(wvs.x), bfhi(wvs.x), bflo(wvs.y), bfhi(wvs.y),
                      bflo(wvs.z), bfhi(wvs.z), bflo(wvs.w), bfhi(wvs.w)};
      float vvw[8] = {bflo(wvv.x), bfhi(wvv.x), bflo(wvv.y), bfhi(wvv.y),
                      bflo(wvv.z), bfhi(wvv.z), bflo(wvv.w), bfhi(wvv.w)};
      vterm = 0.f;
#pragma unroll
      for (int u = 0; u < 8; ++u) {
        float xu0 = xr[u * 3], xu1 = xr[u * 3 + 1], xu2 = xr[u * 3 + 2];
        float xui = (ii == 0) ? xu0 : (ii == 1) ? xu1 : xu2;
        float xi1 = (ii == 0) ? xu1 : (ii == 1) ? xu2 : xu0;  // xv[(ii+1)%3]
        float xi2 = (ii == 0) ? xu2 : (ii == 1) ? xu0 : xu1;  // xv[(ii+2)%3]
        float crs = xi1 * s2 - xi2 * s1;                       // cross(xv_u, sh)[ii]
        vterm += xui * vsw[u] + crs * vvw[u];
      }
    }
    if (lane < 56) msg[(size_t)e * 56 + lane] = a * mult + vterm;
  }
}

// ---------- block-2 message, src-node-major ----------
__global__ __launch_bounds__(256) void k_msg2n(
    const int* __restrict__ rowptr_s, const int* __restrict__ eidx_s,
    const float* __restrict__ sh, const float* __restrict__ h,
    const ushort16* __restrict__ Pb, const float* __restrict__ xv,
    const ushort16* __restrict__ Wedge, float* __restrict__ msg) {
  int n = __builtin_amdgcn_readfirstlane(blockIdx.x * 4 + (threadIdx.x >> 6));
  int lane = threadIdx.x & 63;
  int c = lane & 15, q = lane >> 4;
  uint4 Pq = *reinterpret_cast<const uint4*>(Pb + (size_t)n * 512 + c * 32 + q * 8);
  const float* xvp = xv + (size_t)n * 24;
  float xr[24];
#pragma unroll
  for (int t = 0; t < 24; ++t) xr[t] = xvp[t];
  int r0 = rowptr_s[n], r1 = rowptr_s[n + 1];
  for (int j = r0; j < r1; ++j) {
    int e = __builtin_amdgcn_readfirstlane(eidx_s[j]);
    float sh0 = sh[e * 3 + 0], sh1 = sh[e * 3 + 1], sh2 = sh[e * 3 + 2];
    const float* hq = h + (size_t)e * 32 + q * 8;
    float a = bflo(Pq.x) * hq[0] + bfhi(Pq.x) * hq[1]
            + bflo(Pq.y) * hq[2] + bfhi(Pq.y) * hq[3]
            + bflo(Pq.z) * hq[4] + bfhi(Pq.z) * hq[5]
            + bflo(Pq.w) * hq[6] + bfhi(Pq.w) * hq[7];
    a += __shfl_xor(a, 16, 64);
    a += __shfl_xor(a, 32, 64);
    float du[8];
#pragma unroll
    for (int u = 0; u < 8; ++u)
      du[u] = K_DOT * (xr[u * 3] * sh0 + xr[u * 3 + 1] * sh1 + xr[u * 3 + 2] * sh2);
    uint4 wv = *reinterpret_cast<const uint4*>(Wedge + (size_t)e * 128 + c * 8);
    float vterm = du[0] * bflo(wv.x) + du[1] * bfhi(wv.x) + du[2] * bflo(wv.y) + du[3] * bfhi(wv.y)
                + du[4] * bflo(wv.z) + du[5] * bfhi(wv.z) + du[6] * bflo(wv.w) + du[7] * bfhi(wv.w);
    if (lane < 16) msg[(size_t)e * 16 + c] = a + vterm;
  }
}

// ---------- CSR gather + LayerNorm: one wave per node ----------
__global__ __launch_bounds__(256) void k_gather_ln(
    const int* __restrict__ rowptr, const int* __restrict__ eidx,
    const float* __restrict__ msg, int D,
    const float* __restrict__ g, const float* __restrict__ b,
    ushort16* __restrict__ xsb, float* __restrict__ xvf, float* __restrict__ outf) {
  int n = __builtin_amdgcn_readfirstlane(blockIdx.x * 4 + (threadIdx.x >> 6));
  int lane = threadIdx.x & 63;
  int r0 = rowptr[n], r1 = rowptr[n + 1];
  float v = 0.f;
  for (int j = r0; j < r1; ++j) {
    int e = eidx[j];
    if (lane < D) v += msg[(size_t)e * D + lane];
  }
  v *= K_PRELN;
  if (lane >= D) v = 0.f;
  float sm = v, sq = v * v;
#pragma unroll
  for (int off = 32; off > 0; off >>= 1) {
    sm += __shfl_xor(sm, off, 64);
    sq += __shfl_xor(sq, off, 64);
  }
  float invD = 1.0f / (float)D;
  float mean = sm * invD;
  float var = sq * invD - mean * mean;
  float rs = rsqrtf(var + 1e-5f);
  float r = (v - mean) * rs * g[lane < D ? lane : 0] + b[lane < D ? lane : 0];
  if (outf) {
    if (lane < D) outf[(size_t)n * D + lane] = r;
  } else {
    if (lane < 32) xsb[(size_t)n * 32 + lane] = f2bf(r);
    else if (lane < 56) xvf[(size_t)n * 24 + lane - 32] = r;
  }
}

extern "C" void kernel_launch(void* const* d_in, const int* in_sizes, int n_in,
                              void* d_out, int out_size, void* d_ws, size_t ws_size,
                              hipStream_t stream) {
  const float* pos = (const float*)d_in[0];
  const int* z = (const int*)d_in[1];
  const int* mol = (const int*)d_in[2];
  const int* esrc = (const int*)d_in[3];
  const int* edst = (const int*)d_in[4];
  const float* Ez = (const float*)d_in[5];
  const float* Em = (const float*)d_in[6];
  const float* b0W1 = (const float*)d_in[7];
  const float* b0W2 = (const float*)d_in[8];
  const float* b0g = (const float*)d_in[9];
  const float* b0b = (const float*)d_in[10];
  const float* b1W1 = (const float*)d_in[11];
  const float* b1W2 = (const float*)d_in[12];
  const float* b1g = (const float*)d_in[13];
  const float* b1b = (const float*)d_in[14];
  const float* b2W1 = (const float*)d_in[15];
  const float* b2W2 = (const float*)d_in[16];
  const float* b2g = (const float*)d_in[17];
  const float* b2b = (const float*)d_in[18];
  float* out = (float*)d_out;

  float* ws = (float*)d_ws;
  size_t o = 0;
  int* combo = (int*)(ws + o); o += NNODES;
  int* deg = (int*)(ws + o); o += 2 * NNODES;        // deg_d | deg_s
  int* fill = (int*)(ws + o); o += 2 * NNODES;       // fill_d | fill_s (contiguous w/ deg for memset)
  int* rowptr = (int*)(ws + o); o += 2 * (NNODES + 1) + 6;  // rowptr_d | rowptr_s
  int* eidx = (int*)(ws + o); o += 2 * NEDGES;       // eidx_d | eidx_s
  ushort16* X0cb = (ushort16*)(ws + o); o += 8192;       // 256x64 bf16
  ushort16* xs1b = (ushort16*)(ws + o); o += 131072;     // 8192x32 bf16
  float* xv1 = ws + o; o += (size_t)NNODES * 24;         // 8192x24 f32
  float* h0 = ws + o; o += (size_t)NEDGES * 32;
  float* h1 = ws + o; o += (size_t)NEDGES * 32;
  float* h2 = ws + o; o += (size_t)NEDGES * 32;
  float* shb = ws + o; o += (size_t)NEDGES * 3;
  ushort16* Bp0 = (ushort16*)(ws + o); o += 40960;       // 80x2x512 bf16
  ushort16* Bp1 = (ushort16*)(ws + o); o += 20480;       // 80x512 bf16
  ushort16* Bp2 = (ushort16*)(ws + o); o += 8192;        // 32x512 bf16
  ushort16* Bpw1 = (ushort16*)(ws + o); o += 6144;       // 24x512 bf16
  ushort16* Bpw2 = (ushort16*)(ws + o); o += 2048;       // 8x512 bf16
  ushort16* h1b = (ushort16*)(ws + o); o += (size_t)NEDGES * 16;   // 65536x32 bf16
  ushort16* h2b = (ushort16*)(ws + o); o += (size_t)NEDGES * 16;
  ushort16* Wedge1 = (ushort16*)(ws + o); o += (size_t)NEDGES * 192;  // 65536x384 bf16
  ushort16* P12 = (ushort16*)(ws + o); o += (size_t)NNODES * 640;     // 8192x1280 bf16
  float* msg56 = ws + o; o += (size_t)NEDGES * 56;       // 65536x56 f32 (14.7 MB)

  int* rowptr_s = rowptr + NNODES + 1;
  int* eidx_s = eidx + NEDGES;
  ushort16* P0c = P12;          // 256x1280 bf16, consumed before gemm1 overwrites
  ushort16* xs2b = xs1b;        // xs1b dead after gemm1
  float* xv2 = xv1;             // xv1 dead after k_msg1n
  ushort16* Wedge2 = Wedge1;    // Wedge1 dead after k_msg1n; 65536x128 bf16 fits
  float* msg16 = msg56;         // block-1 msg dead after gather1

  hipMemsetAsync(deg, 0, 4 * NNODES * sizeof(int), stream);

  k_prep<<<960, 256, 0, stream>>>(pos, z, mol, esrc, edst, Ez, Em,
                                  b0W1, b1W1, b2W1, b0W2, b1W2, b2W2,
                                  combo, X0cb, shb, h0, h1, h2, h1b, h2b,
                                  Bp0, Bp1, Bp2, Bpw1, Bpw2, deg);
  k_scan<<<2, 256, 0, stream>>>(deg, rowptr);
  k_fill<<<512, 256, 0, stream>>>(esrc, edst, rowptr, fill, eidx);

  // block 0
  k_gemm_mfma<<<dim3(4, 20), 256, 0, stream>>>(X0cb, Bp0, P0c, 1280, 64);
  k_gemm_mfma<<<dim3(1024, 6), 256, 0, stream>>>(h1b, Bpw1, Wedge1, 384, 32);
  k_msg0n<<<2048, 256, 0, stream>>>(rowptr_s, eidx_s, combo, shb, h0, P0c, msg56);
  k_gather_ln<<<2048, 256, 0, stream>>>(rowptr, eidx, msg56, 56, b0g, b0b, xs1b, xv1, nullptr);

  // block 1
  k_gemm_mfma<<<dim3(128, 20), 256, 0, stream>>>(xs1b, Bp1, P12, 1280, 32);
  k_msg1n<<<2048, 256, 0, stream>>>(rowptr_s, eidx_s, shb, h1, P12, xv1, Wedge1, msg56);
  k_gather_ln<<<2048, 256, 0, stream>>>(rowptr, eidx, msg56, 56, b1g, b1b, xs2b, xv2, nullptr);

  // block 2 (Wedge2 overwrites Wedge1 -- safe after k_msg1n)
  k_gemm_mfma<<<dim3(1024, 2), 256, 0, stream>>>(h2b, Bpw2, Wedge2, 128, 32);
  k_gemm_mfma<<<dim3(128, 8), 256, 0, stream>>>(xs2b, Bp2, P12, 512, 32);
  k_msg2n<<<2048, 256, 0, stream>>>(rowptr_s, eidx_s, shb, h2, P12, xv2, Wedge2, msg16);
  k_gather_ln<<<2048, 256, 0, stream>>>(rowptr, eidx, msg16, 16, b2g, b2b, nullptr, nullptr, out);
}

// Round 4
// 256.536 us; speedup vs baseline: 1.0276x; 1.0276x over previous
//
#include <hip/hip_runtime.h>

#define NNODES 8192
#define NEDGES 65536

#define K_PACK   0.02209708691f   // 1/sqrt(2048)
#define K_P1SV   0.01804219593f   // 1/(32*sqrt3)
#define K_VVS    0.04419417382f   // 1/sqrt(512)
#define K_VS     0.03608439182f   // 1/(16*sqrt3)
#define K_VVV    0.02551551815f   // K_VS/sqrt2
#define K_DOT    0.57735026919f
#define K_PRELN  0.35355339059f
#define C_EMB    8.4335730689f

typedef unsigned int uint32;
typedef unsigned short ushort16;
typedef __attribute__((ext_vector_type(8))) short short8;
typedef __attribute__((ext_vector_type(4))) float floatx4;

__device__ __forceinline__ float siluf(float x) { return x / (1.0f + __expf(-x)); }
__device__ __forceinline__ float susf(float t) { return t > 0.0f ? __expf(-1.0f / t) : 0.0f; }
__device__ __forceinline__ ushort16 f2bf(float f) {
  uint32 u = __float_as_uint(f);
  return (ushort16)((u + 0x7fffu + ((u >> 16) & 1u)) >> 16);
}
__device__ __forceinline__ float bflo(uint32 v) { return __uint_as_float(v << 16); }
__device__ __forceinline__ float bfhi(uint32 v) { return __uint_as_float(v & 0xffff0000u); }

__device__ __forceinline__ void mlp32(const float* __restrict__ W, const float emb[10],
                                      float* __restrict__ H) {
#pragma unroll
  for (int m = 0; m < 32; ++m) {
    float t = 0.f;
#pragma unroll
    for (int k = 0; k < 10; ++k) t += emb[k] * W[k * 32 + m];
    H[m] = siluf(t);
  }
}

// ---------- prep: edge geom + 3 MLPs (bf16 out), deg, combo, X0cb, B packs ----------
__global__ __launch_bounds__(256) void k_prep(
    const float* __restrict__ pos, const int* __restrict__ z, const int* __restrict__ mol,
    const int* __restrict__ esrc, const int* __restrict__ edst,
    const float* __restrict__ Ez, const float* __restrict__ Em,
    const float* __restrict__ W10, const float* __restrict__ W11, const float* __restrict__ W12,
    const float* __restrict__ W20, const float* __restrict__ W21, const float* __restrict__ W22,
    int* __restrict__ combo, ushort16* __restrict__ X0cb, float* __restrict__ sh,
    ushort16* __restrict__ h0b, ushort16* __restrict__ h1b, ushort16* __restrict__ h2b,
    ushort16* __restrict__ Bp0, ushort16* __restrict__ Bp1, ushort16* __restrict__ Bp2,
    ushort16* __restrict__ Bpw1, ushort16* __restrict__ Bpw2, int* __restrict__ deg) {
  int idx = blockIdx.x * 256 + threadIdx.x;
  if (idx < NEDGES) {
    int e = idx;
    int s = esrc[e], d = edst[e];
    atomicAdd(&deg[d], 1);
    float vx = pos[d * 3 + 0] - pos[s * 3 + 0];
    float vy = pos[d * 3 + 1] - pos[s * 3 + 1];
    float vz = pos[d * 3 + 2] - pos[s * 3 + 2];
    float len = sqrtf(vx * vx + vy * vy + vz * vz);
    float inv = 1.7320508076f / fmaxf(len, 1e-9f);
    sh[e * 3 + 0] = vx * inv; sh[e * 3 + 1] = vy * inv; sh[e * 3 + 2] = vz * inv;
    float emb[10];
#pragma unroll
    for (int k = 0; k < 10; ++k) {
      float u = len * 1.1f - (float)(k + 1);
      emb[k] = C_EMB * susf(u + 1.0f) * susf(1.0f - u);
    }
    float H[32];
    uint32* hp;
    mlp32(W10, emb, H);
    hp = (uint32*)(h0b + (size_t)e * 32);
#pragma unroll
    for (int m = 0; m < 16; ++m)
      hp[m] = (uint32)f2bf(H[2 * m]) | ((uint32)f2bf(H[2 * m + 1]) << 16);
    mlp32(W11, emb, H);
    hp = (uint32*)(h1b + (size_t)e * 32);
#pragma unroll
    for (int m = 0; m < 16; ++m)
      hp[m] = (uint32)f2bf(H[2 * m]) | ((uint32)f2bf(H[2 * m + 1]) << 16);
    mlp32(W12, emb, H);
    hp = (uint32*)(h2b + (size_t)e * 32);
#pragma unroll
    for (int m = 0; m < 16; ++m)
      hp[m] = (uint32)f2bf(H[2 * m]) | ((uint32)f2bf(H[2 * m + 1]) << 16);
    return;
  }
  idx -= NEDGES;
  if (idx < NNODES) { combo[idx] = z[idx] * 2 + mol[idx]; return; }
  idx -= NNODES;
  if (idx < 16384) {  // X0cb[256][64] bf16
    int c = idx >> 6, j = idx & 63;
    float v = 0.f;
    if (c < 200) {
      int zz = c >> 1, mm = c & 1;
      v = (j < 48) ? Ez[zz * 48 + j] : Em[mm * 16 + (j - 48)];
    }
    X0cb[idx] = f2bf(v);
    return;
  }
  idx -= 16384;
  if (idx < 81920) {  // Bp0[tile(80)][kh(2)][lane(64)][j(8)] bf16, K=64
    int tile = idx >> 10; int r = idx & 1023;
    int kh = r >> 9; int rr = r & 511;
    int lane = rr >> 3, j = rr & 7;
    int k = kh * 32 + (lane >> 4) * 8 + j;
    int n = tile * 16 + (lane & 15);
    int c = n >> 5, m = n & 31;
    int col = (c < 32) ? (k * 32 + c) : (2048 + k * 8 + (c - 32));
    Bp0[idx] = f2bf(W20[m * 2560 + col] * K_PACK);
    return;
  }
  idx -= 81920;
  if (idx < 40960) {  // Bp1[tile(80)][lane][j] bf16, K=32
    int tile = idx >> 9; int rr = idx & 511;
    int lane = rr >> 3, j = rr & 7;
    int k = (lane >> 4) * 8 + j;
    int n = tile * 16 + (lane & 15);
    int c = n >> 5, m = n & 31;
    float v = (c < 32) ? W21[m * 1664 + k * 32 + c] * K_PACK
                       : W21[m * 1664 + 1280 + k * 8 + (c - 32)] * K_P1SV;
    Bp1[idx] = f2bf(v);
    return;
  }
  idx -= 40960;
  if (idx < 16384) {  // Bp2[tile(32)][lane][j] bf16, K=32
    int tile = idx >> 9; int rr = idx & 511;
    int lane = rr >> 3, j = rr & 7;
    int k = (lane >> 4) * 8 + j;
    int n = tile * 16 + (lane & 15);
    int c = n >> 5, m = n & 31;
    Bp2[idx] = f2bf(W22[m * 640 + k * 16 + c] * K_PACK);
    return;
  }
  idx -= 16384;
  if (idx < 12288) {  // Bpw1[tile(24)][lane][j] bf16, K=32 -> per-edge vvs/vs/vvv weights
    int tile = idx >> 9; int rr = idx & 511;
    int lane = rr >> 3, j = rr & 7;
    int m = (lane >> 4) * 8 + j;
    int c = tile * 16 + (lane & 15);
    float v;
    if (c < 256) {              // c = u*32 + w  (vvs)
      int u = c >> 5, w = c & 31;
      v = W21[m * 1664 + 1024 + u * 32 + w] * K_VVS;
    } else {                    // c = 256 + (u*8+v)*2 + t  (t=0: vs, t=1: vvv)
      int r2 = c - 256; int t = r2 & 1; int l2 = r2 >> 1;
      int u = l2 >> 3, vv = l2 & 7;
      v = (t == 0) ? W21[m * 1664 + 1536 + u * 8 + vv] * K_VS
                   : W21[m * 1664 + 1600 + u * 8 + vv] * K_VVV;
    }
    Bpw1[idx] = f2bf(v);
    return;
  }
  idx -= 12288;
  {  // Bpw2[tile(8)][lane][j] bf16, K=32 -> block-2 vvs weights, c = (u*8+wh)*2 + t
    int tile = idx >> 9; int rr = idx & 511;
    int lane = rr >> 3, j = rr & 7;
    int m = (lane >> 4) * 8 + j;
    int c = tile * 16 + (lane & 15);
    int t = c & 1; int l2 = c >> 1;
    int u = l2 >> 3, wh = l2 & 7;
    Bpw2[idx] = f2bf(W22[m * 640 + 512 + u * 16 + wh * 2 + t] * K_VVS);
  }
}

// ---------- exclusive scan of deg[8192] -> rowptr[8193] (one block) ----------
__global__ __launch_bounds__(256) void k_scan(const int* __restrict__ deg,
                                              int* __restrict__ rowptr) {
  __shared__ int sums[256];
  int t = threadIdx.x;
  int base = t * 32;
  int local[32];
  int s = 0;
#pragma unroll
  for (int i = 0; i < 32; ++i) { local[i] = s; s += deg[base + i]; }
  sums[t] = s;
  __syncthreads();
  for (int off = 1; off < 256; off <<= 1) {
    int v = (t >= off) ? sums[t - off] : 0;
    __syncthreads();
    sums[t] += v;
    __syncthreads();
  }
  int prev = (t == 0) ? 0 : sums[t - 1];
#pragma unroll
  for (int i = 0; i < 32; ++i) rowptr[base + i] = prev + local[i];
  if (t == 255) rowptr[NNODES] = sums[255];
}

// ---------- fill CSR edge index ----------
__global__ __launch_bounds__(256) void k_fill(const int* __restrict__ edst,
                                              const int* __restrict__ rowptr,
                                              int* __restrict__ fill, int* __restrict__ eidx) {
  int e = blockIdx.x * 256 + threadIdx.x;
  if (e >= NEDGES) return;
  int d = edst[e];
  int p = atomicAdd(&fill[d], 1);
  eidx[rowptr[d] + p] = e;
}

// ---------- MFMA GEMM tile body ----------
__device__ __forceinline__ void gemm_tile(
    const ushort16* __restrict__ A, const ushort16* __restrict__ Bp, ushort16* __restrict__ C,
    int N, int K, int bx, int by, int wave, int lane) {
  int m0 = bx * 64 + wave * 16;
  int n0 = by * 64;
  int row = lane & 15, q = lane >> 4;
  int nkh = K >> 5;
  floatx4 acc[4];
  floatx4 zero = {0.f, 0.f, 0.f, 0.f};
#pragma unroll
  for (int t = 0; t < 4; ++t) acc[t] = zero;
  for (int kh = 0; kh < nkh; ++kh) {
    short8 a = *reinterpret_cast<const short8*>(A + (size_t)(m0 + row) * K + kh * 32 + q * 8);
#pragma unroll
    for (int t = 0; t < 4; ++t) {
      int T = (n0 >> 4) + t;
      short8 b = *reinterpret_cast<const short8*>(Bp + ((size_t)T * nkh + kh) * 512 + lane * 8);
      acc[t] = __builtin_amdgcn_mfma_f32_16x16x32_bf16(a, b, acc[t], 0, 0, 0);
    }
  }
  int colb = n0 + row;
#pragma unroll
  for (int t = 0; t < 4; ++t)
#pragma unroll
    for (int r = 0; r < 4; ++r)
      C[(size_t)(m0 + q * 4 + r) * N + colb + t * 16] = f2bf(acc[t][r]);
}

__global__ __launch_bounds__(256) void k_gemm_mfma(
    const ushort16* __restrict__ A, const ushort16* __restrict__ Bp, ushort16* __restrict__ C,
    int N, int K) {
  gemm_tile(A, Bp, C, N, K, blockIdx.x, blockIdx.y, threadIdx.x >> 6, threadIdx.x & 63);
}

// ---------- merged 3-job GEMM (all depend only on k_prep) ----------
__global__ __launch_bounds__(256) void k_gemm3(
    const ushort16* __restrict__ A0, const ushort16* __restrict__ B0, ushort16* __restrict__ C0,
    int N0, int K0, int nbx0, int nb0,
    const ushort16* __restrict__ A1, const ushort16* __restrict__ B1, ushort16* __restrict__ C1,
    int N1, int K1, int nbx1, int nb1,
    const ushort16* __restrict__ A2, const ushort16* __restrict__ B2, ushort16* __restrict__ C2,
    int N2, int K2, int nbx2) {
  int b = blockIdx.x;
  int wave = threadIdx.x >> 6, lane = threadIdx.x & 63;
  if (b < nb0) {
    gemm_tile(A0, B0, C0, N0, K0, b % nbx0, b / nbx0, wave, lane);
  } else if (b < nb0 + nb1) {
    b -= nb0;
    gemm_tile(A1, B1, C1, N1, K1, b % nbx1, b / nbx1, wave, lane);
  } else {
    b -= nb0 + nb1;
    gemm_tile(A2, B2, C2, N2, K2, b % nbx2, b / nbx2, wave, lane);
  }
}

// ---------- block-0 message: P-gather, h in bf16, write msg row ----------
__global__ __launch_bounds__(256) void k_msg0(
    const int* __restrict__ rowmap, const int* __restrict__ esrc,
    const float* __restrict__ sh, const ushort16* __restrict__ hb,
    const ushort16* __restrict__ Pb, float* __restrict__ msg) {
  int e = __builtin_amdgcn_readfirstlane(blockIdx.x * 4 + (threadIdx.x >> 6));
  int lane = threadIdx.x & 63;
  int s = esrc[e];
  int row = rowmap[s];
  float sh0 = sh[e * 3 + 0], sh1 = sh[e * 3 + 1], sh2 = sh[e * 3 + 2];
  int c; float mult;
  if (lane < 32) { c = lane; mult = 1.0f; }
  else if (lane < 56) {
    int l = lane - 32; int v = l / 3; int i = l - v * 3;
    c = 32 + v;
    mult = (i == 0) ? sh0 : (i == 1 ? sh1 : sh2);
  } else { c = 0; mult = 0.0f; }
  const uint4* Hp = reinterpret_cast<const uint4*>(hb + (size_t)e * 32);
  const uint4* Pp = reinterpret_cast<const uint4*>(Pb + (size_t)row * 1280 + c * 32);
  float a = 0.f;
#pragma unroll
  for (int qq = 0; qq < 4; ++qq) {
    uint4 pv = Pp[qq];
    uint4 hv = Hp[qq];
    a += bflo(pv.x) * bflo(hv.x) + bfhi(pv.x) * bfhi(hv.x);
    a += bflo(pv.y) * bflo(hv.y) + bfhi(pv.y) * bfhi(hv.y);
    a += bflo(pv.z) * bflo(hv.z) + bfhi(pv.z) * bfhi(hv.z);
    a += bflo(pv.w) * bflo(hv.w) + bfhi(pv.w) * bfhi(hv.w);
  }
  if (lane < 56) msg[(size_t)e * 56 + lane] = a * mult;
}

// ---------- block-1 message: fused P-gather (bf16 h) + vector paths ----------
__global__ __launch_bounds__(256) void k_msg1(
    const int* __restrict__ esrc, const float* __restrict__ sh, const ushort16* __restrict__ hb,
    const ushort16* __restrict__ Pb, const float* __restrict__ xv,
    const ushort16* __restrict__ Wedge, float* __restrict__ msg) {
  __shared__ float vbuf[4][56];
  int w = threadIdx.x >> 6;
  int e = __builtin_amdgcn_readfirstlane(blockIdx.x * 4 + w);
  int lane = threadIdx.x & 63;
  int s = esrc[e];
  float sh0 = sh[e * 3 + 0], sh1 = sh[e * 3 + 1], sh2 = sh[e * 3 + 2];
  // ---- V path: lane = u*8 + wq ----
  int u = lane >> 3;
  const float* xvp = xv + (size_t)s * 24 + u * 3;
  float x0 = xvp[0], x1 = xvp[1], x2 = xvp[2];
  float du = K_DOT * (x0 * sh0 + x1 * sh1 + x2 * sh2);
  float cr0 = x1 * sh2 - x2 * sh1;
  float cr1 = x2 * sh0 - x0 * sh2;
  float cr2 = x0 * sh1 - x1 * sh0;
  const ushort16* wp = Wedge + (size_t)e * 384;
  uint2 wv = *reinterpret_cast<const uint2*>(wp + lane * 4);
  uint32 wsv = *reinterpret_cast<const uint32*>(wp + 256 + lane * 2);
  float b0 = du * bflo(wv.x), b1 = du * bfhi(wv.x);
  float b2 = du * bflo(wv.y), b3 = du * bfhi(wv.y);
  float avs = bflo(wsv), avv = bfhi(wsv);
  float e0v = x0 * avs + cr0 * avv;
  float e1v = x1 * avs + cr1 * avv;
  float e2v = x2 * avs + cr2 * avv;
#pragma unroll
  for (int off = 8; off < 64; off <<= 1) {
    b0 += __shfl_xor(b0, off, 64); b1 += __shfl_xor(b1, off, 64);
    b2 += __shfl_xor(b2, off, 64); b3 += __shfl_xor(b3, off, 64);
    e0v += __shfl_xor(e0v, off, 64); e1v += __shfl_xor(e1v, off, 64);
    e2v += __shfl_xor(e2v, off, 64);
  }
  if (lane < 8) {
    vbuf[w][lane * 4 + 0] = b0; vbuf[w][lane * 4 + 1] = b1;
    vbuf[w][lane * 4 + 2] = b2; vbuf[w][lane * 4 + 3] = b3;
    vbuf[w][32 + lane * 3 + 0] = e0v;
    vbuf[w][32 + lane * 3 + 1] = e1v;
    vbuf[w][32 + lane * 3 + 2] = e2v;
  }
  // ---- P path: lane = channel ----
  int c; float mult;
  if (lane < 32) { c = lane; mult = 1.0f; }
  else if (lane < 56) {
    int l = lane - 32; int v = l / 3; int i = l - v * 3;
    c = 32 + v;
    mult = (i == 0) ? sh0 : (i == 1 ? sh1 : sh2);
  } else { c = 0; mult = 0.0f; }
  const uint4* Hp = reinterpret_cast<const uint4*>(hb + (size_t)e * 32);
  const uint4* Pp = reinterpret_cast<const uint4*>(Pb + (size_t)s * 1280 + c * 32);
  float a = 0.f;
#pragma unroll
  for (int qq = 0; qq < 4; ++qq) {
    uint4 pv = Pp[qq];
    uint4 hv = Hp[qq];
    a += bflo(pv.x) * bflo(hv.x) + bfhi(pv.x) * bfhi(hv.x);
    a += bflo(pv.y) * bflo(hv.y) + bfhi(pv.y) * bfhi(hv.y);
    a += bflo(pv.z) * bflo(hv.z) + bfhi(pv.z) * bfhi(hv.z);
    a += bflo(pv.w) * bflo(hv.w) + bfhi(pv.w) * bfhi(hv.w);
  }
  __syncthreads();
  if (lane < 56) msg[(size_t)e * 56 + lane] = a * mult + vbuf[w][lane];
}

// ---------- block-2 message: fused P-gather (bf16 h) + vvs path ----------
__global__ __launch_bounds__(256) void k_msg2(
    const int* __restrict__ esrc, const float* __restrict__ sh, const ushort16* __restrict__ hb,
    const ushort16* __restrict__ Pb, const float* __restrict__ xv,
    const ushort16* __restrict__ Wedge, float* __restrict__ msg) {
  __shared__ float vbuf[4][16];
  int w = threadIdx.x >> 6;
  int e = __builtin_amdgcn_readfirstlane(blockIdx.x * 4 + w);
  int lane = threadIdx.x & 63;
  int s = esrc[e];
  float sh0 = sh[e * 3 + 0], sh1 = sh[e * 3 + 1], sh2 = sh[e * 3 + 2];
  // ---- V path: lane = u*8 + wh ----
  int u = lane >> 3;
  const float* xvp = xv + (size_t)s * 24 + u * 3;
  float du = K_DOT * (xvp[0] * sh0 + xvp[1] * sh1 + xvp[2] * sh2);
  uint32 w2 = *reinterpret_cast<const uint32*>(Wedge + (size_t)e * 128 + lane * 2);
  float c0 = du * bflo(w2), c1 = du * bfhi(w2);
#pragma unroll
  for (int off = 8; off < 64; off <<= 1) {
    c0 += __shfl_xor(c0, off, 64); c1 += __shfl_xor(c1, off, 64);
  }
  if (lane < 8) { vbuf[w][lane * 2 + 0] = c0; vbuf[w][lane * 2 + 1] = c1; }
  // ---- P path: lane = q*16 + wc ----
  int q = lane >> 4, wc = lane & 15;
  uint4 hv = reinterpret_cast<const uint4*>(hb + (size_t)e * 32)[q];
  uint4 pv = reinterpret_cast<const uint4*>(Pb + (size_t)s * 512 + wc * 32)[q];
  float a = bflo(pv.x) * bflo(hv.x) + bfhi(pv.x) * bfhi(hv.x)
          + bflo(pv.y) * bflo(hv.y) + bfhi(pv.y) * bfhi(hv.y)
          + bflo(pv.z) * bflo(hv.z) + bfhi(pv.z) * bfhi(hv.z)
          + bflo(pv.w) * bflo(hv.w) + bfhi(pv.w) * bfhi(hv.w);
  a += __shfl_xor(a, 16, 64);
  a += __shfl_xor(a, 32, 64);
  __syncthreads();
  if (lane < 16) msg[(size_t)e * 16 + lane] = a + vbuf[w][lane];
}

// ---------- CSR gather + LayerNorm: one wave per node ----------
__global__ __launch_bounds__(256) void k_gather_ln(
    const int* __restrict__ rowptr, const int* __restrict__ eidx,
    const float* __restrict__ msg, int D,
    const float* __restrict__ g, const float* __restrict__ b,
    ushort16* __restrict__ xsb, float* __restrict__ xvf, float* __restrict__ outf) {
  int n = __builtin_amdgcn_readfirstlane(blockIdx.x * 4 + (threadIdx.x >> 6));
  int lane = threadIdx.x & 63;
  int r0 = rowptr[n], r1 = rowptr[n + 1];
  float v = 0.f;
  for (int j = r0; j < r1; ++j) {
    int e = eidx[j];
    if (lane < D) v += msg[(size_t)e * D + lane];
  }
  v *= K_PRELN;
  if (lane >= D) v = 0.f;
  float sm = v, sq = v * v;
#pragma unroll
  for (int off = 32; off > 0; off >>= 1) {
    sm += __shfl_xor(sm, off, 64);
    sq += __shfl_xor(sq, off, 64);
  }
  float invD = 1.0f / (float)D;
  float mean = sm * invD;
  float var = sq * invD - mean * mean;
  float rs = rsqrtf(var + 1e-5f);
  float r = (v - mean) * rs * g[lane < D ? lane : 0] + b[lane < D ? lane : 0];
  if (outf) {
    if (lane < D) outf[(size_t)n * D + lane] = r;
  } else {
    if (lane < 32) xsb[(size_t)n * 32 + lane] = f2bf(r);
    else if (lane < 56) xvf[(size_t)n * 24 + lane - 32] = r;
  }
}

extern "C" void kernel_launch(void* const* d_in, const int* in_sizes, int n_in,
                              void* d_out, int out_size, void* d_ws, size_t ws_size,
                              hipStream_t stream) {
  const float* pos = (const float*)d_in[0];
  const int* z = (const int*)d_in[1];
  const int* mol = (const int*)d_in[2];
  const int* esrc = (const int*)d_in[3];
  const int* edst = (const int*)d_in[4];
  const float* Ez = (const float*)d_in[5];
  const float* Em = (const float*)d_in[6];
  const float* b0W1 = (const float*)d_in[7];
  const float* b0W2 = (const float*)d_in[8];
  const float* b0g = (const float*)d_in[9];
  const float* b0b = (const float*)d_in[10];
  const float* b1W1 = (const float*)d_in[11];
  const float* b1W2 = (const float*)d_in[12];
  const float* b1g = (const float*)d_in[13];
  const float* b1b = (const float*)d_in[14];
  const float* b2W1 = (const float*)d_in[15];
  const float* b2W2 = (const float*)d_in[16];
  const float* b2g = (const float*)d_in[17];
  const float* b2b = (const float*)d_in[18];
  float* out = (float*)d_out;

  float* ws = (float*)d_ws;
  size_t o = 0;
  int* combo = (int*)(ws + o); o += NNODES;
  int* deg = (int*)(ws + o); o += NNODES;            // deg+fill contiguous (one memset)
  int* fill = (int*)(ws + o); o += NNODES;
  int* rowptr = (int*)(ws + o); o += NNODES + 8;
  int* eidx = (int*)(ws + o); o += NEDGES;
  ushort16* X0cb = (ushort16*)(ws + o); o += 8192;       // 256x64 bf16
  ushort16* xs1b = (ushort16*)(ws + o); o += 131072;     // 8192x32 bf16
  float* xv1 = ws + o; o += (size_t)NNODES * 24;         // 8192x24 f32
  ushort16* h0b = (ushort16*)(ws + o); o += (size_t)NEDGES * 16;   // 65536x32 bf16
  ushort16* h1b = (ushort16*)(ws + o); o += (size_t)NEDGES * 16;
  ushort16* h2b = (ushort16*)(ws + o); o += (size_t)NEDGES * 16;
  float* shb = ws + o; o += (size_t)NEDGES * 3;
  ushort16* Bp0 = (ushort16*)(ws + o); o += 40960;       // 80x2x512 bf16
  ushort16* Bp1 = (ushort16*)(ws + o); o += 20480;       // 80x512 bf16
  ushort16* Bp2 = (ushort16*)(ws + o); o += 8192;        // 32x512 bf16
  ushort16* Bpw1 = (ushort16*)(ws + o); o += 6144;       // 24x512 bf16
  ushort16* Bpw2 = (ushort16*)(ws + o); o += 2048;       // 8x512 bf16
  ushort16* Wedge1 = (ushort16*)(ws + o); o += (size_t)NEDGES * 192;  // 65536x384 bf16
  ushort16* Wedge2 = (ushort16*)(ws + o); o += (size_t)NEDGES * 64;   // 65536x128 bf16
  ushort16* P12 = (ushort16*)(ws + o); o += (size_t)NNODES * 640;     // 8192x1280 bf16
  float* msg56 = ws + o; o += (size_t)NEDGES * 56;       // 65536x56 f32 (14.7 MB)

  ushort16* P0c = P12;          // 256x1280 bf16, consumed (msg0) before gemm1 overwrites
  ushort16* xs2b = xs1b;        // xs1b dead after gemm P12-1
  float* xv2 = xv1;             // xv1 dead after k_msg1
  float* msg16 = msg56;         // block-1 msg dead after gather1

  hipMemsetAsync(deg, 0, 2 * NNODES * sizeof(int), stream);

  k_prep<<<960, 256, 0, stream>>>(pos, z, mol, esrc, edst, Ez, Em,
                                  b0W1, b1W1, b2W1, b0W2, b1W2, b2W2,
                                  combo, X0cb, shb, h0b, h1b, h2b,
                                  Bp0, Bp1, Bp2, Bpw1, Bpw2, deg);
  k_scan<<<1, 256, 0, stream>>>(deg, rowptr);
  k_fill<<<256, 256, 0, stream>>>(edst, rowptr, fill, eidx);

  // one merged launch: Wedge1 (6144 wg) + Wedge2 (2048 wg) + P0c (80 wg)
  k_gemm3<<<8272, 256, 0, stream>>>(h1b, Bpw1, Wedge1, 384, 32, 1024, 6144,
                                    h2b, Bpw2, Wedge2, 128, 32, 1024, 2048,
                                    X0cb, Bp0, P0c, 1280, 64, 4);

  // block 0
  k_msg0<<<16384, 256, 0, stream>>>(combo, esrc, shb, h0b, P0c, msg56);
  k_gather_ln<<<2048, 256, 0, stream>>>(rowptr, eidx, msg56, 56, b0g, b0b, xs1b, xv1, nullptr);

  // block 1
  k_gemm_mfma<<<dim3(128, 20), 256, 0, stream>>>(xs1b, Bp1, P12, 1280, 32);
  k_msg1<<<16384, 256, 0, stream>>>(esrc, shb, h1b, P12, xv1, Wedge1, msg56);
  k_gather_ln<<<2048, 256, 0, stream>>>(rowptr, eidx, msg56, 56, b1g, b1b, xs2b, xv2, nullptr);

  // block 2
  k_gemm_mfma<<<dim3(128, 8), 256, 0, stream>>>(xs2b, Bp2, P12, 512, 32);
  k_msg2<<<16384, 256, 0, stream>>>(esrc, shb, h2b, P12, xv2, Wedge2, msg16);
  k_gather_ln<<<2048, 256, 0, stream>>>(rowptr, eidx, msg16, 16, b2g, b2b, nullptr, nullptr, out);
}

// Round 5
// 245.866 us; speedup vs baseline: 1.0721x; 1.0434x over previous
//
#include <hip/hip_runtime.h>

#define NNODES 8192
#define NEDGES 65536

#define K_PACK   0.02209708691f   // 1/sqrt(2048)
#define K_P1SV   0.01804219593f   // 1/(32*sqrt3)
#define K_VVS    0.04419417382f   // 1/sqrt(512)
#define K_VS     0.03608439182f   // 1/(16*sqrt3)
#define K_VVV    0.02551551815f   // K_VS/sqrt2
#define K_DOT    0.57735026919f
#define K_PRELN  0.35355339059f
#define C_EMB    8.4335730689f

typedef unsigned int uint32;
typedef unsigned short ushort16;
typedef __attribute__((ext_vector_type(8))) short short8;
typedef __attribute__((ext_vector_type(4))) float floatx4;

__device__ __forceinline__ float siluf(float x) { return x / (1.0f + __expf(-x)); }
__device__ __forceinline__ float susf(float t) { return t > 0.0f ? __expf(-1.0f / t) : 0.0f; }
__device__ __forceinline__ ushort16 f2bf(float f) {
  uint32 u = __float_as_uint(f);
  return (ushort16)((u + 0x7fffu + ((u >> 16) & 1u)) >> 16);
}
__device__ __forceinline__ float bflo(uint32 v) { return __uint_as_float(v << 16); }
__device__ __forceinline__ float bfhi(uint32 v) { return __uint_as_float(v & 0xffff0000u); }
__device__ __forceinline__ float bfs(ushort16 v) { return __uint_as_float((uint32)v << 16); }

__device__ __forceinline__ void mlp32(const float* __restrict__ W, const float emb[10],
                                      float* __restrict__ H) {
#pragma unroll
  for (int m = 0; m < 32; ++m) {
    float t = 0.f;
#pragma unroll
    for (int k = 0; k < 10; ++k) t += emb[k] * W[k * 32 + m];
    H[m] = siluf(t);
  }
}

// ---------- prep: edge geom + 3 MLPs (bf16), direct-bucket CSR, combo, X0cb, B packs ----------
__global__ __launch_bounds__(256) void k_prep(
    const float* __restrict__ pos, const int* __restrict__ z, const int* __restrict__ mol,
    const int* __restrict__ esrc, const int* __restrict__ edst,
    const float* __restrict__ Ez, const float* __restrict__ Em,
    const float* __restrict__ W10, const float* __restrict__ W11, const float* __restrict__ W12,
    const float* __restrict__ W20, const float* __restrict__ W21, const float* __restrict__ W22,
    int* __restrict__ combo, ushort16* __restrict__ X0cb, float* __restrict__ sh,
    ushort16* __restrict__ h0b, ushort16* __restrict__ h1b, ushort16* __restrict__ h2b,
    ushort16* __restrict__ Bp0, ushort16* __restrict__ Bp1, ushort16* __restrict__ Bp2,
    ushort16* __restrict__ Bpw1, ushort16* __restrict__ Bpw2,
    int* __restrict__ deg, int* __restrict__ eidx) {
  int idx = blockIdx.x * 256 + threadIdx.x;
  if (idx < NEDGES) {
    int e = idx;
    int s = esrc[e], d = edst[e];
    int p = atomicAdd(&deg[d], 1);
    if (p < 64) eidx[(size_t)d * 64 + p] = e;
    float vx = pos[d * 3 + 0] - pos[s * 3 + 0];
    float vy = pos[d * 3 + 1] - pos[s * 3 + 1];
    float vz = pos[d * 3 + 2] - pos[s * 3 + 2];
    float len = sqrtf(vx * vx + vy * vy + vz * vz);
    float inv = 1.7320508076f / fmaxf(len, 1e-9f);
    sh[e * 3 + 0] = vx * inv; sh[e * 3 + 1] = vy * inv; sh[e * 3 + 2] = vz * inv;
    float emb[10];
#pragma unroll
    for (int k = 0; k < 10; ++k) {
      float u = len * 1.1f - (float)(k + 1);
      emb[k] = C_EMB * susf(u + 1.0f) * susf(1.0f - u);
    }
    float H[32];
    uint32* hp;
    mlp32(W10, emb, H);
    hp = (uint32*)(h0b + (size_t)e * 32);
#pragma unroll
    for (int m = 0; m < 16; ++m)
      hp[m] = (uint32)f2bf(H[2 * m]) | ((uint32)f2bf(H[2 * m + 1]) << 16);
    mlp32(W11, emb, H);
    hp = (uint32*)(h1b + (size_t)e * 32);
#pragma unroll
    for (int m = 0; m < 16; ++m)
      hp[m] = (uint32)f2bf(H[2 * m]) | ((uint32)f2bf(H[2 * m + 1]) << 16);
    mlp32(W12, emb, H);
    hp = (uint32*)(h2b + (size_t)e * 32);
#pragma unroll
    for (int m = 0; m < 16; ++m)
      hp[m] = (uint32)f2bf(H[2 * m]) | ((uint32)f2bf(H[2 * m + 1]) << 16);
    return;
  }
  idx -= NEDGES;
  if (idx < NNODES) { combo[idx] = z[idx] * 2 + mol[idx]; return; }
  idx -= NNODES;
  if (idx < 16384) {  // X0cb[256][64] bf16
    int c = idx >> 6, j = idx & 63;
    float v = 0.f;
    if (c < 200) {
      int zz = c >> 1, mm = c & 1;
      v = (j < 48) ? Ez[zz * 48 + j] : Em[mm * 16 + (j - 48)];
    }
    X0cb[idx] = f2bf(v);
    return;
  }
  idx -= 16384;
  if (idx < 81920) {  // Bp0[tile(80)][kh(2)][lane(64)][j(8)] bf16, K=64
    int tile = idx >> 10; int r = idx & 1023;
    int kh = r >> 9; int rr = r & 511;
    int lane = rr >> 3, j = rr & 7;
    int k = kh * 32 + (lane >> 4) * 8 + j;
    int n = tile * 16 + (lane & 15);
    int c = n >> 5, m = n & 31;
    int col = (c < 32) ? (k * 32 + c) : (2048 + k * 8 + (c - 32));
    Bp0[idx] = f2bf(W20[m * 2560 + col] * K_PACK);
    return;
  }
  idx -= 81920;
  if (idx < 40960) {  // Bp1[tile(80)][lane][j] bf16, K=32
    int tile = idx >> 9; int rr = idx & 511;
    int lane = rr >> 3, j = rr & 7;
    int k = (lane >> 4) * 8 + j;
    int n = tile * 16 + (lane & 15);
    int c = n >> 5, m = n & 31;
    float v = (c < 32) ? W21[m * 1664 + k * 32 + c] * K_PACK
                       : W21[m * 1664 + 1280 + k * 8 + (c - 32)] * K_P1SV;
    Bp1[idx] = f2bf(v);
    return;
  }
  idx -= 40960;
  if (idx < 16384) {  // Bp2[tile(32)][lane][j] bf16, K=32
    int tile = idx >> 9; int rr = idx & 511;
    int lane = rr >> 3, j = rr & 7;
    int k = (lane >> 4) * 8 + j;
    int n = tile * 16 + (lane & 15);
    int c = n >> 5, m = n & 31;
    Bp2[idx] = f2bf(W22[m * 640 + k * 16 + c] * K_PACK);
    return;
  }
  idx -= 16384;
  if (idx < 12288) {  // Bpw1[tile(24)][lane][j] bf16, K=32 -> per-edge vvs/vs/vvv weights
    int tile = idx >> 9; int rr = idx & 511;
    int lane = rr >> 3, j = rr & 7;
    int m = (lane >> 4) * 8 + j;
    int c = tile * 16 + (lane & 15);
    float v;
    if (c < 256) {              // c = u*32 + w  (vvs)
      int u = c >> 5, w = c & 31;
      v = W21[m * 1664 + 1024 + u * 32 + w] * K_VVS;
    } else {                    // c = 256 + (u*8+v)*2 + t  (t=0: vs, t=1: vvv)
      int r2 = c - 256; int t = r2 & 1; int l2 = r2 >> 1;
      int u = l2 >> 3, vv = l2 & 7;
      v = (t == 0) ? W21[m * 1664 + 1536 + u * 8 + vv] * K_VS
                   : W21[m * 1664 + 1600 + u * 8 + vv] * K_VVV;
    }
    Bpw1[idx] = f2bf(v);
    return;
  }
  idx -= 12288;
  {  // Bpw2[tile(8)][lane][j] bf16, K=32 -> block-2 vvs weights, c = (u*8+wh)*2 + t
    int tile = idx >> 9; int rr = idx & 511;
    int lane = rr >> 3, j = rr & 7;
    int m = (lane >> 4) * 8 + j;
    int c = tile * 16 + (lane & 15);
    int t = c & 1; int l2 = c >> 1;
    int u = l2 >> 3, wh = l2 & 7;
    Bpw2[idx] = f2bf(W22[m * 640 + 512 + u * 16 + wh * 2 + t] * K_VVS);
  }
}

// ---------- MFMA GEMM tile body ----------
__device__ __forceinline__ void gemm_tile(
    const ushort16* __restrict__ A, const ushort16* __restrict__ Bp, ushort16* __restrict__ C,
    int N, int K, int bx, int by, int wave, int lane) {
  int m0 = bx * 64 + wave * 16;
  int n0 = by * 64;
  int row = lane & 15, q = lane >> 4;
  int nkh = K >> 5;
  floatx4 acc[4];
  floatx4 zero = {0.f, 0.f, 0.f, 0.f};
#pragma unroll
  for (int t = 0; t < 4; ++t) acc[t] = zero;
  for (int kh = 0; kh < nkh; ++kh) {
    short8 a = *reinterpret_cast<const short8*>(A + (size_t)(m0 + row) * K + kh * 32 + q * 8);
#pragma unroll
    for (int t = 0; t < 4; ++t) {
      int T = (n0 >> 4) + t;
      short8 b = *reinterpret_cast<const short8*>(Bp + ((size_t)T * nkh + kh) * 512 + lane * 8);
      acc[t] = __builtin_amdgcn_mfma_f32_16x16x32_bf16(a, b, acc[t], 0, 0, 0);
    }
  }
  int colb = n0 + row;
#pragma unroll
  for (int t = 0; t < 4; ++t)
#pragma unroll
    for (int r = 0; r < 4; ++r)
      C[(size_t)(m0 + q * 4 + r) * N + colb + t * 16] = f2bf(acc[t][r]);
}

__global__ __launch_bounds__(256) void k_gemm_mfma(
    const ushort16* __restrict__ A, const ushort16* __restrict__ Bp, ushort16* __restrict__ C,
    int N, int K) {
  gemm_tile(A, Bp, C, N, K, blockIdx.x, blockIdx.y, threadIdx.x >> 6, threadIdx.x & 63);
}

// ---------- merged 3-job GEMM (all depend only on k_prep) ----------
__global__ __launch_bounds__(256) void k_gemm3(
    const ushort16* __restrict__ A0, const ushort16* __restrict__ B0, ushort16* __restrict__ C0,
    int N0, int K0, int nbx0, int nb0,
    const ushort16* __restrict__ A1, const ushort16* __restrict__ B1, ushort16* __restrict__ C1,
    int N1, int K1, int nbx1, int nb1,
    const ushort16* __restrict__ A2, const ushort16* __restrict__ B2, ushort16* __restrict__ C2,
    int N2, int K2, int nbx2) {
  int b = blockIdx.x;
  int wave = threadIdx.x >> 6, lane = threadIdx.x & 63;
  if (b < nb0) {
    gemm_tile(A0, B0, C0, N0, K0, b % nbx0, b / nbx0, wave, lane);
  } else if (b < nb0 + nb1) {
    b -= nb0;
    gemm_tile(A1, B1, C1, N1, K1, b % nbx1, b / nbx1, wave, lane);
  } else {
    b -= nb0 + nb1;
    gemm_tile(A2, B2, C2, N2, K2, b % nbx2, b / nbx2, wave, lane);
  }
}

// ---------- block-0 message: P-gather, bf16 msg out ----------
__global__ __launch_bounds__(256) void k_msg0(
    const int* __restrict__ rowmap, const int* __restrict__ esrc,
    const float* __restrict__ sh, const ushort16* __restrict__ hb,
    const ushort16* __restrict__ Pb, ushort16* __restrict__ msg) {
  int e = __builtin_amdgcn_readfirstlane(blockIdx.x * 4 + (threadIdx.x >> 6));
  int lane = threadIdx.x & 63;
  int s = esrc[e];
  int row = rowmap[s];
  float sh0 = sh[e * 3 + 0], sh1 = sh[e * 3 + 1], sh2 = sh[e * 3 + 2];
  int c; float mult;
  if (lane < 32) { c = lane; mult = 1.0f; }
  else if (lane < 56) {
    int l = lane - 32; int v = l / 3; int i = l - v * 3;
    c = 32 + v;
    mult = (i == 0) ? sh0 : (i == 1 ? sh1 : sh2);
  } else { c = 0; mult = 0.0f; }
  const uint4* Hp = reinterpret_cast<const uint4*>(hb + (size_t)e * 32);
  const uint4* Pp = reinterpret_cast<const uint4*>(Pb + (size_t)row * 1280 + c * 32);
  float a = 0.f;
#pragma unroll
  for (int qq = 0; qq < 4; ++qq) {
    uint4 pv = Pp[qq];
    uint4 hv = Hp[qq];
    a += bflo(pv.x) * bflo(hv.x) + bfhi(pv.x) * bfhi(hv.x);
    a += bflo(pv.y) * bflo(hv.y) + bfhi(pv.y) * bfhi(hv.y);
    a += bflo(pv.z) * bflo(hv.z) + bfhi(pv.z) * bfhi(hv.z);
    a += bflo(pv.w) * bflo(hv.w) + bfhi(pv.w) * bfhi(hv.w);
  }
  if (lane < 56) msg[(size_t)e * 56 + lane] = f2bf(a * mult);
}

// ---------- block-1 message: fused P-gather + vector paths, bf16 msg out ----------
__global__ __launch_bounds__(256) void k_msg1(
    const int* __restrict__ esrc, const float* __restrict__ sh, const ushort16* __restrict__ hb,
    const ushort16* __restrict__ Pb, const float* __restrict__ xv,
    const ushort16* __restrict__ Wedge, ushort16* __restrict__ msg) {
  __shared__ float vbuf[4][56];
  int w = threadIdx.x >> 6;
  int e = __builtin_amdgcn_readfirstlane(blockIdx.x * 4 + w);
  int lane = threadIdx.x & 63;
  int s = esrc[e];
  float sh0 = sh[e * 3 + 0], sh1 = sh[e * 3 + 1], sh2 = sh[e * 3 + 2];
  // ---- V path: lane = u*8 + wq ----
  int u = lane >> 3;
  const float* xvp = xv + (size_t)s * 24 + u * 3;
  float x0 = xvp[0], x1 = xvp[1], x2 = xvp[2];
  float du = K_DOT * (x0 * sh0 + x1 * sh1 + x2 * sh2);
  float cr0 = x1 * sh2 - x2 * sh1;
  float cr1 = x2 * sh0 - x0 * sh2;
  float cr2 = x0 * sh1 - x1 * sh0;
  const ushort16* wp = Wedge + (size_t)e * 384;
  uint2 wv = *reinterpret_cast<const uint2*>(wp + lane * 4);
  uint32 wsv = *reinterpret_cast<const uint32*>(wp + 256 + lane * 2);
  float b0 = du * bflo(wv.x), b1 = du * bfhi(wv.x);
  float b2 = du * bflo(wv.y), b3 = du * bfhi(wv.y);
  float avs = bflo(wsv), avv = bfhi(wsv);
  float e0v = x0 * avs + cr0 * avv;
  float e1v = x1 * avs + cr1 * avv;
  float e2v = x2 * avs + cr2 * avv;
#pragma unroll
  for (int off = 8; off < 64; off <<= 1) {
    b0 += __shfl_xor(b0, off, 64); b1 += __shfl_xor(b1, off, 64);
    b2 += __shfl_xor(b2, off, 64); b3 += __shfl_xor(b3, off, 64);
    e0v += __shfl_xor(e0v, off, 64); e1v += __shfl_xor(e1v, off, 64);
    e2v += __shfl_xor(e2v, off, 64);
  }
  if (lane < 8) {
    vbuf[w][lane * 4 + 0] = b0; vbuf[w][lane * 4 + 1] = b1;
    vbuf[w][lane * 4 + 2] = b2; vbuf[w][lane * 4 + 3] = b3;
    vbuf[w][32 + lane * 3 + 0] = e0v;
    vbuf[w][32 + lane * 3 + 1] = e1v;
    vbuf[w][32 + lane * 3 + 2] = e2v;
  }
  // ---- P path: lane = channel ----
  int c; float mult;
  if (lane < 32) { c = lane; mult = 1.0f; }
  else if (lane < 56) {
    int l = lane - 32; int v = l / 3; int i = l - v * 3;
    c = 32 + v;
    mult = (i == 0) ? sh0 : (i == 1 ? sh1 : sh2);
  } else { c = 0; mult = 0.0f; }
  const uint4* Hp = reinterpret_cast<const uint4*>(hb + (size_t)e * 32);
  const uint4* Pp = reinterpret_cast<const uint4*>(Pb + (size_t)s * 1280 + c * 32);
  float a = 0.f;
#pragma unroll
  for (int qq = 0; qq < 4; ++qq) {
    uint4 pv = Pp[qq];
    uint4 hv = Hp[qq];
    a += bflo(pv.x) * bflo(hv.x) + bfhi(pv.x) * bfhi(hv.x);
    a += bflo(pv.y) * bflo(hv.y) + bfhi(pv.y) * bfhi(hv.y);
    a += bflo(pv.z) * bflo(hv.z) + bfhi(pv.z) * bfhi(hv.z);
    a += bflo(pv.w) * bflo(hv.w) + bfhi(pv.w) * bfhi(hv.w);
  }
  __syncthreads();
  if (lane < 56) msg[(size_t)e * 56 + lane] = f2bf(a * mult + vbuf[w][lane]);
}

// ---------- block-2 message: fused P-gather + vvs path, bf16 msg out ----------
__global__ __launch_bounds__(256) void k_msg2(
    const int* __restrict__ esrc, const float* __restrict__ sh, const ushort16* __restrict__ hb,
    const ushort16* __restrict__ Pb, const float* __restrict__ xv,
    const ushort16* __restrict__ Wedge, ushort16* __restrict__ msg) {
  __shared__ float vbuf[4][16];
  int w = threadIdx.x >> 6;
  int e = __builtin_amdgcn_readfirstlane(blockIdx.x * 4 + w);
  int lane = threadIdx.x & 63;
  int s = esrc[e];
  float sh0 = sh[e * 3 + 0], sh1 = sh[e * 3 + 1], sh2 = sh[e * 3 + 2];
  // ---- V path: lane = u*8 + wh ----
  int u = lane >> 3;
  const float* xvp = xv + (size_t)s * 24 + u * 3;
  float du = K_DOT * (xvp[0] * sh0 + xvp[1] * sh1 + xvp[2] * sh2);
  uint32 w2 = *reinterpret_cast<const uint32*>(Wedge + (size_t)e * 128 + lane * 2);
  float c0 = du * bflo(w2), c1 = du * bfhi(w2);
#pragma unroll
  for (int off = 8; off < 64; off <<= 1) {
    c0 += __shfl_xor(c0, off, 64); c1 += __shfl_xor(c1, off, 64);
  }
  if (lane < 8) { vbuf[w][lane * 2 + 0] = c0; vbuf[w][lane * 2 + 1] = c1; }
  // ---- P path: lane = q*16 + wc ----
  int q = lane >> 4, wc = lane & 15;
  uint4 hv = reinterpret_cast<const uint4*>(hb + (size_t)e * 32)[q];
  uint4 pv = reinterpret_cast<const uint4*>(Pb + (size_t)s * 512 + wc * 32)[q];
  float a = bflo(pv.x) * bflo(hv.x) + bfhi(pv.x) * bfhi(hv.x)
          + bflo(pv.y) * bflo(hv.y) + bfhi(pv.y) * bfhi(hv.y)
          + bflo(pv.z) * bflo(hv.z) + bfhi(pv.z) * bfhi(hv.z)
          + bflo(pv.w) * bflo(hv.w) + bfhi(pv.w) * bfhi(hv.w);
  a += __shfl_xor(a, 16, 64);
  a += __shfl_xor(a, 32, 64);
  __syncthreads();
  if (lane < 16) msg[(size_t)e * 16 + lane] = f2bf(a + vbuf[w][lane]);
}

// ---------- bucket gather + LayerNorm: one wave per node ----------
__global__ __launch_bounds__(256) void k_gather_ln(
    const int* __restrict__ deg, const int* __restrict__ eidx,
    const ushort16* __restrict__ msg, int D,
    const float* __restrict__ g, const float* __restrict__ b,
    ushort16* __restrict__ xsb, float* __restrict__ xvf, float* __restrict__ outf) {
  int n = __builtin_amdgcn_readfirstlane(blockIdx.x * 4 + (threadIdx.x >> 6));
  int lane = threadIdx.x & 63;
  int cnt = deg[n]; if (cnt > 64) cnt = 64;
  const int* ep = eidx + (size_t)n * 64;
  float v = 0.f;
  for (int j = 0; j < cnt; ++j) {
    int e = ep[j];
    if (lane < D) v += bfs(msg[(size_t)e * D + lane]);
  }
  v *= K_PRELN;
  if (lane >= D) v = 0.f;
  float sm = v, sq = v * v;
#pragma unroll
  for (int off = 32; off > 0; off >>= 1) {
    sm += __shfl_xor(sm, off, 64);
    sq += __shfl_xor(sq, off, 64);
  }
  float invD = 1.0f / (float)D;
  float mean = sm * invD;
  float var = sq * invD - mean * mean;
  float rs = rsqrtf(var + 1e-5f);
  float r = (v - mean) * rs * g[lane < D ? lane : 0] + b[lane < D ? lane : 0];
  if (outf) {
    if (lane < D) outf[(size_t)n * D + lane] = r;
  } else {
    if (lane < 32) xsb[(size_t)n * 32 + lane] = f2bf(r);
    else if (lane < 56) xvf[(size_t)n * 24 + lane - 32] = r;
  }
}

extern "C" void kernel_launch(void* const* d_in, const int* in_sizes, int n_in,
                              void* d_out, int out_size, void* d_ws, size_t ws_size,
                              hipStream_t stream) {
  const float* pos = (const float*)d_in[0];
  const int* z = (const int*)d_in[1];
  const int* mol = (const int*)d_in[2];
  const int* esrc = (const int*)d_in[3];
  const int* edst = (const int*)d_in[4];
  const float* Ez = (const float*)d_in[5];
  const float* Em = (const float*)d_in[6];
  const float* b0W1 = (const float*)d_in[7];
  const float* b0W2 = (const float*)d_in[8];
  const float* b0g = (const float*)d_in[9];
  const float* b0b = (const float*)d_in[10];
  const float* b1W1 = (const float*)d_in[11];
  const float* b1W2 = (const float*)d_in[12];
  const float* b1g = (const float*)d_in[13];
  const float* b1b = (const float*)d_in[14];
  const float* b2W1 = (const float*)d_in[15];
  const float* b2W2 = (const float*)d_in[16];
  const float* b2g = (const float*)d_in[17];
  const float* b2b = (const float*)d_in[18];
  float* out = (float*)d_out;

  float* ws = (float*)d_ws;
  size_t o = 0;
  int* combo = (int*)(ws + o); o += NNODES;
  int* deg = (int*)(ws + o); o += NNODES;
  int* eidx = (int*)(ws + o); o += (size_t)NNODES * 64;  // fixed-capacity buckets
  ushort16* X0cb = (ushort16*)(ws + o); o += 8192;       // 256x64 bf16
  ushort16* xs1b = (ushort16*)(ws + o); o += 131072;     // 8192x32 bf16
  float* xv1 = ws + o; o += (size_t)NNODES * 24;         // 8192x24 f32
  ushort16* h0b = (ushort16*)(ws + o); o += (size_t)NEDGES * 16;   // 65536x32 bf16
  ushort16* h1b = (ushort16*)(ws + o); o += (size_t)NEDGES * 16;
  ushort16* h2b = (ushort16*)(ws + o); o += (size_t)NEDGES * 16;
  float* shb = ws + o; o += (size_t)NEDGES * 3;
  ushort16* Bp0 = (ushort16*)(ws + o); o += 40960;       // 80x2x512 bf16
  ushort16* Bp1 = (ushort16*)(ws + o); o += 20480;       // 80x512 bf16
  ushort16* Bp2 = (ushort16*)(ws + o); o += 8192;        // 32x512 bf16
  ushort16* Bpw1 = (ushort16*)(ws + o); o += 6144;       // 24x512 bf16
  ushort16* Bpw2 = (ushort16*)(ws + o); o += 2048;       // 8x512 bf16
  ushort16* Wedge1 = (ushort16*)(ws + o); o += (size_t)NEDGES * 192;  // 65536x384 bf16
  ushort16* Wedge2 = (ushort16*)(ws + o); o += (size_t)NEDGES * 64;   // 65536x128 bf16
  ushort16* P12 = (ushort16*)(ws + o); o += (size_t)NNODES * 640;     // 8192x1280 bf16
  ushort16* msgb = (ushort16*)(ws + o); o += (size_t)NEDGES * 28;     // 65536x56 bf16 (7.3 MB)

  ushort16* P0c = P12;          // 256x1280 bf16, consumed (msg0) before gemm1 overwrites
  ushort16* xs2b = xs1b;        // xs1b dead after gemm P12-1
  float* xv2 = xv1;             // xv1 dead after k_msg1
  ushort16* msg16 = msgb;       // block-1 msg dead after gather1

  hipMemsetAsync(deg, 0, NNODES * sizeof(int), stream);

  k_prep<<<960, 256, 0, stream>>>(pos, z, mol, esrc, edst, Ez, Em,
                                  b0W1, b1W1, b2W1, b0W2, b1W2, b2W2,
                                  combo, X0cb, shb, h0b, h1b, h2b,
                                  Bp0, Bp1, Bp2, Bpw1, Bpw2, deg, eidx);

  // one merged launch: Wedge1 (6144 wg) + Wedge2 (2048 wg) + P0c (80 wg)
  k_gemm3<<<8272, 256, 0, stream>>>(h1b, Bpw1, Wedge1, 384, 32, 1024, 6144,
                                    h2b, Bpw2, Wedge2, 128, 32, 1024, 2048,
                                    X0cb, Bp0, P0c, 1280, 64, 4);

  // block 0
  k_msg0<<<16384, 256, 0, stream>>>(combo, esrc, shb, h0b, P0c, msgb);
  k_gather_ln<<<2048, 256, 0, stream>>>(deg, eidx, msgb, 56, b0g, b0b, xs1b, xv1, nullptr);

  // block 1
  k_gemm_mfma<<<dim3(128, 20), 256, 0, stream>>>(xs1b, Bp1, P12, 1280, 32);
  k_msg1<<<16384, 256, 0, stream>>>(esrc, shb, h1b, P12, xv1, Wedge1, msgb);
  k_gather_ln<<<2048, 256, 0, stream>>>(deg, eidx, msgb, 56, b1g, b1b, xs2b, xv2, nullptr);

  // block 2
  k_gemm_mfma<<<dim3(128, 8), 256, 0, stream>>>(xs2b, Bp2, P12, 512, 32);
  k_msg2<<<16384, 256, 0, stream>>>(esrc, shb, h2b, P12, xv2, Wedge2, msg16);
  k_gather_ln<<<2048, 256, 0, stream>>>(deg, eidx, msg16, 16, b2g, b2b, nullptr, nullptr, out);
}